// Round 13
// baseline (85.855 us; speedup 1.0000x reference)
//
#include <hip/hip_runtime.h>
#include <hip/hip_bf16.h>

#define N_NODES 100000
#define D 64
#define BSHIFT 8
#define BNODES 256        // nodes per bucket
#define NB 391            // ceil(100000/256)
#define CHUNK 8192
#define SLICES 4
#define SCOLS 16          // columns per slice; slab = N_NODES*SCOLS*2B = 3.2 MB < 4 MB XCD-L2

typedef __attribute__((ext_vector_type(8))) _Float16 half8;
typedef __attribute__((ext_vector_type(4))) _Float16 half4;

// ---------- K1: f32 -> f16 column-sliced layout + per-(chunk,bucket) histogram ----------
// feat16T[s][r][c] : 4 contiguous slabs of N_NODES x 16 fp16
__global__ void convhist(const float4* __restrict__ feat4, _Float16* __restrict__ feat16T,
                         const int* __restrict__ dst, int* __restrict__ counts,
                         int nchunk, int n_edges) {
    int total = N_NODES * SLICES;
    for (int i = blockIdx.x * blockDim.x + threadIdx.x; i < total;
         i += gridDim.x * blockDim.x) {
        int s = i & 3, r = i >> 2;
        const float4* rp = feat4 + (size_t)r * 16 + s * 4;   // row r: 16 float4s
        float4 a = rp[0], b = rp[1], c = rp[2], d = rp[3];
        half8 h0, h1;
        h0[0] = (_Float16)a.x; h0[1] = (_Float16)a.y; h0[2] = (_Float16)a.z; h0[3] = (_Float16)a.w;
        h0[4] = (_Float16)b.x; h0[5] = (_Float16)b.y; h0[6] = (_Float16)b.z; h0[7] = (_Float16)b.w;
        h1[0] = (_Float16)c.x; h1[1] = (_Float16)c.y; h1[2] = (_Float16)c.z; h1[3] = (_Float16)c.w;
        h1[4] = (_Float16)d.x; h1[5] = (_Float16)d.y; h1[6] = (_Float16)d.z; h1[7] = (_Float16)d.w;
        _Float16* w = feat16T + ((size_t)s * N_NODES + r) * SCOLS;
        *reinterpret_cast<half8*>(w) = h0;
        *reinterpret_cast<half8*>(w + 8) = h1;
    }
    __shared__ int h[NB];
    int c = blockIdx.x;
    if (c >= nchunk) return;
    for (int i = threadIdx.x; i < NB; i += blockDim.x) h[i] = 0;
    __syncthreads();
    int s = c * CHUNK, e = min(s + CHUNK, n_edges);
    for (int i = s + threadIdx.x; i < e; i += blockDim.x)
        atomicAdd(&h[dst[i] >> BSHIFT], 1);
    __syncthreads();
    for (int b = threadIdx.x; b < NB; b += blockDim.x)
        counts[(size_t)b * nchunk + c] = h[b];   // bucket-major
}

// ---------- K2: per-bucket exclusive scan over chunk counts ----------
__global__ void scanB(int* __restrict__ counts, int* __restrict__ totals, int nchunk) {
    __shared__ int s[256];
    int b = blockIdx.x;
    int tid = threadIdx.x;
    int carry = 0;
    int* row = counts + (size_t)b * nchunk;
    for (int t0 = 0; t0 < nchunk; t0 += 256) {
        int i = t0 + tid;
        int v = (i < nchunk) ? row[i] : 0;
        s[tid] = v;
        __syncthreads();
        for (int off = 1; off < 256; off <<= 1) {
            int t = (tid >= off) ? s[tid - off] : 0;
            __syncthreads();
            s[tid] += t;
            __syncthreads();
        }
        if (i < nchunk) row[i] = s[tid] - v + carry;
        carry += s[255];
        __syncthreads();
    }
    if (tid == 0) totals[b] = carry;
}

// ---------- K2b: exclusive scan of totals -> bucket base (one block, NB<=1024) ----------
__global__ void baseK(const int* __restrict__ totals, int* __restrict__ base,
                      int n_edges) {
    __shared__ int s[1024];
    int tid = threadIdx.x;
    int v = (tid < NB) ? totals[tid] : 0;
    s[tid] = v;
    __syncthreads();
    for (int off = 1; off < 1024; off <<= 1) {
        int t = (tid >= off) ? s[tid - off] : 0;
        __syncthreads();
        s[tid] += t;
        __syncthreads();
    }
    if (tid < NB) base[tid] = s[tid] - v;
    if (tid == 0) base[NB] = n_edges;
}

// ---------- K3: scatter to bucket order ----------
__global__ void scatter2(const int* __restrict__ src, const int* __restrict__ dst,
                         const int* __restrict__ counts, const int* __restrict__ base,
                         unsigned* __restrict__ sorted, int nchunk, int n_edges) {
    __shared__ int cur[NB];
    int tid = threadIdx.x;      // 1024
    int c = blockIdx.x;
    for (int b = tid; b < NB; b += blockDim.x)
        cur[b] = base[b] + counts[(size_t)b * nchunk + c];
    __syncthreads();
    int s = c * CHUNK, e = min(s + CHUNK, n_edges);
    for (int i = s + tid; i < e; i += blockDim.x) {
        int d = dst[i];
        int b = d >> BSHIFT;
        int r = atomicAdd(&cur[b], 1);
        sorted[r] = ((unsigned)(d & (BNODES - 1)) << 17) | (unsigned)src[i];
    }
}

// ---------- K4: per-bucket counting sort -> global sorted2 (src) + CSR node_off ----------
__global__ void sortN(const unsigned* __restrict__ sorted, const int* __restrict__ base,
                      int* __restrict__ sorted2, int* __restrict__ node_off,
                      int n_edges) {
    __shared__ int cnt[BNODES];
    __shared__ int scn[BNODES];
    __shared__ int cur[BNODES];
    int tid = threadIdx.x;      // 1024
    int b = blockIdx.x;
    int start = base[b];
    int cntb = base[b + 1] - start;
    bool big = (cntb > 4096);

    unsigned p0 = 0, p1 = 0, p2 = 0, p3 = 0;
    int i0 = tid, i1 = tid + 1024, i2 = tid + 2048, i3 = tid + 3072;
    if (!big) {
        if (i0 < cntb) p0 = sorted[start + i0];
        if (i1 < cntb) p1 = sorted[start + i1];
        if (i2 < cntb) p2 = sorted[start + i2];
        if (i3 < cntb) p3 = sorted[start + i3];
    }

    if (tid < BNODES) cnt[tid] = 0;
    __syncthreads();
    if (!big) {
        if (i0 < cntb) atomicAdd(&cnt[(p0 >> 17) & (BNODES - 1)], 1);
        if (i1 < cntb) atomicAdd(&cnt[(p1 >> 17) & (BNODES - 1)], 1);
        if (i2 < cntb) atomicAdd(&cnt[(p2 >> 17) & (BNODES - 1)], 1);
        if (i3 < cntb) atomicAdd(&cnt[(p3 >> 17) & (BNODES - 1)], 1);
    } else {
        for (int i = tid; i < cntb; i += 1024)
            atomicAdd(&cnt[(sorted[start + i] >> 17) & (BNODES - 1)], 1);
    }
    __syncthreads();

    int v = (tid < BNODES) ? cnt[tid] : 0;
    if (tid < BNODES) scn[tid] = v;
    __syncthreads();
    for (int off = 1; off < BNODES; off <<= 1) {
        int t = 0;
        if (tid < BNODES && tid >= off) t = scn[tid - off];
        __syncthreads();
        if (tid < BNODES) scn[tid] += t;
        __syncthreads();
    }
    if (tid < BNODES) cur[tid] = scn[tid] - v;
    __syncthreads();

    if (tid < BNODES) {
        int node = (b << BSHIFT) + tid;
        if (node < N_NODES) node_off[node] = start + (scn[tid] - v);
    }
    if (b == NB - 1 && tid == 0) node_off[N_NODES] = n_edges;

    if (!big) {
        if (i0 < cntb) { int q = atomicAdd(&cur[(p0 >> 17) & (BNODES - 1)], 1); sorted2[start + q] = (int)(p0 & 0x1FFFF); }
        if (i1 < cntb) { int q = atomicAdd(&cur[(p1 >> 17) & (BNODES - 1)], 1); sorted2[start + q] = (int)(p1 & 0x1FFFF); }
        if (i2 < cntb) { int q = atomicAdd(&cur[(p2 >> 17) & (BNODES - 1)], 1); sorted2[start + q] = (int)(p2 & 0x1FFFF); }
        if (i3 < cntb) { int q = atomicAdd(&cur[(p3 >> 17) & (BNODES - 1)], 1); sorted2[start + q] = (int)(p3 & 0x1FFFF); }
    } else {
        for (int i = tid; i < cntb; i += 1024) {
            unsigned p = sorted[start + i];
            int q = atomicAdd(&cur[(p >> 17) & (BNODES - 1)], 1);
            sorted2[start + q] = (int)(p & 0x1FFFF);
        }
    }
}

// ---------- K5: XCD-sliced CSR gather ----------
// blockIdx = bucket*4 + slice  => slice s runs on XCDs {s, s+4} (round-robin dispatch),
// so each XCD's L2 holds only its 3.2 MB slab.
__global__ void gatherS(const _Float16* __restrict__ feat16T,
                        const int* __restrict__ sorted2,
                        const int* __restrict__ node_off,
                        float* __restrict__ out) {
    int b = blockIdx.x >> 2;
    int sl = blockIdx.x & 3;
    int g = threadIdx.x >> 2;      // node within bucket (0..255)
    int gl = threadIdx.x & 3;      // lane in 4-lane group: 4 fp16 (8 B)
    int node = (b << BSHIFT) + g;
    if (node >= N_NODES) return;
    int off = node_off[node];
    int end = node_off[node + 1];
    int deg = end - off;
    const _Float16* slab = feat16T + (size_t)sl * N_NODES * SCOLS;

    float4 acc = make_float4(0.f, 0.f, 0.f, 0.f);
    int e = off;
    for (; e + 4 <= end; e += 4) {
        int se = sorted2[e + gl];
        int s0 = __shfl(se, 0, 4);
        int s1 = __shfl(se, 1, 4);
        int s2 = __shfl(se, 2, 4);
        int s3 = __shfl(se, 3, 4);
        half4 v0 = *reinterpret_cast<const half4*>(slab + (size_t)s0 * SCOLS + gl * 4);
        half4 v1 = *reinterpret_cast<const half4*>(slab + (size_t)s1 * SCOLS + gl * 4);
        half4 v2 = *reinterpret_cast<const half4*>(slab + (size_t)s2 * SCOLS + gl * 4);
        half4 v3 = *reinterpret_cast<const half4*>(slab + (size_t)s3 * SCOLS + gl * 4);
        acc.x += (float)v0[0] + (float)v1[0] + (float)v2[0] + (float)v3[0];
        acc.y += (float)v0[1] + (float)v1[1] + (float)v2[1] + (float)v3[1];
        acc.z += (float)v0[2] + (float)v1[2] + (float)v2[2] + (float)v3[2];
        acc.w += (float)v0[3] + (float)v1[3] + (float)v2[3] + (float)v3[3];
    }
    for (; e < end; e++) {
        int s = sorted2[e];
        half4 vv = *reinterpret_cast<const half4*>(slab + (size_t)s * SCOLS + gl * 4);
        acc.x += (float)vv[0]; acc.y += (float)vv[1];
        acc.z += (float)vv[2]; acc.w += (float)vv[3];
    }
    float inv = (deg > 0) ? 1.0f / (float)deg : 0.0f;
    float4 o = make_float4(acc.x * inv, acc.y * inv, acc.z * inv, acc.w * inv);
    *reinterpret_cast<float4*>(&out[(size_t)node * D + sl * SCOLS + gl * 4]) = o;
}

// ---------- fallback (atomic scatter) if ws too small ----------
__global__ void gcn_scatter(const float* __restrict__ feat, const int* __restrict__ src,
                            const int* __restrict__ dst, float* __restrict__ out,
                            float* __restrict__ deg, int n_edges) {
    long long gtid = (long long)blockIdx.x * blockDim.x + threadIdx.x;
    int edge = (int)(gtid >> 6);
    int lane = threadIdx.x & 63;
    if (edge >= n_edges) return;
    atomicAdd(&out[(long long)dst[edge] * D + lane],
              feat[(long long)src[edge] * D + lane]);
    if (lane == 0) atomicAdd(&deg[dst[edge]], 1.0f);
}
__global__ void gcn_finalize(float* __restrict__ out, const float* __restrict__ deg,
                             int total) {
    int i = blockIdx.x * blockDim.x + threadIdx.x;
    if (i >= total) return;
    float dg = deg[i >> 6];
    out[i] = (dg > 0.0f) ? out[i] / dg : 0.0f;
}

extern "C" void kernel_launch(void* const* d_in, const int* in_sizes, int n_in,
                              void* d_out, int out_size, void* d_ws, size_t ws_size,
                              hipStream_t stream) {
    const float* feat = (const float*)d_in[0];
    const int* src = (const int*)d_in[1];
    const int* dst = (const int*)d_in[2];
    float* out = (float*)d_out;
    int n_edges = in_sizes[1];

    int nchunk = (n_edges + CHUNK - 1) / CHUNK;
    size_t ncounts = (size_t)NB * nchunk;
    size_t f16_bytes = (size_t)N_NODES * D * sizeof(_Float16);   // 12.8 MB (sliced)
    size_t need = f16_bytes
                + (ncounts + NB + NB + 1 + N_NODES + 1) * sizeof(int)
                + (size_t)n_edges * 2 * sizeof(int);

    if (ws_size < need) {
        float* deg = (float*)d_ws;
        int total = N_NODES * D;
        hipMemsetAsync(out, 0, (size_t)total * sizeof(float), stream);
        hipMemsetAsync(deg, 0, (size_t)N_NODES * sizeof(float), stream);
        long long threads = (long long)n_edges * 64;
        int grid = (int)((threads + 255) / 256);
        gcn_scatter<<<grid, 256, 0, stream>>>(feat, src, dst, out, deg, n_edges);
        gcn_finalize<<<(total + 255) / 256, 256, 0, stream>>>(out, deg, total);
        return;
    }

    char* wp = (char*)d_ws;
    _Float16* feat16T = (_Float16*)wp;           wp += f16_bytes;
    int* counts = (int*)wp;                      wp += ncounts * sizeof(int);
    int* totals = (int*)wp;                      wp += (size_t)NB * sizeof(int);
    int* base = (int*)wp;                        wp += (size_t)(NB + 1) * sizeof(int);
    int* node_off = (int*)wp;                    wp += (size_t)(N_NODES + 1) * sizeof(int);
    unsigned* sorted = (unsigned*)wp;            wp += (size_t)n_edges * sizeof(unsigned);
    int* sorted2 = (int*)wp;

    int chgrid = (nchunk > 256) ? nchunk : 256;
    convhist<<<chgrid, 1024, 0, stream>>>((const float4*)feat, feat16T,
                                          dst, counts, nchunk, n_edges);
    scanB<<<NB, 256, 0, stream>>>(counts, totals, nchunk);
    baseK<<<1, 1024, 0, stream>>>(totals, base, n_edges);
    scatter2<<<nchunk, 1024, 0, stream>>>(src, dst, counts, base, sorted,
                                          nchunk, n_edges);
    sortN<<<NB, 1024, 0, stream>>>(sorted, base, sorted2, node_off, n_edges);
    gatherS<<<NB * SLICES, 1024, 0, stream>>>(feat16T, sorted2, node_off, out);
}

// Round 14
// 65.272 us; speedup vs baseline: 1.3153x; 1.3153x over previous
//
#include <hip/hip_runtime.h>
#include <hip/hip_bf16.h>

#define N_NODES 100000
#define D 64
#define BSHIFT 8
#define BNODES 256        // nodes per bucket
#define NB 391            // ceil(100000/256)
#define CHUNK 8192
#define LDS_CAP 4096      // edges per bucket in LDS (mean 3200, sd ~56)

typedef __attribute__((ext_vector_type(8))) _Float16 half8;

// ---------- K1: feature f32->f16 conversion + per-(chunk,bucket) histogram ----------
__global__ void convhist(const float4* __restrict__ feat4, float4* __restrict__ feat16,
                         int n4pairs, const int* __restrict__ dst, int* __restrict__ counts,
                         int nchunk, int n_edges) {
    for (int i = blockIdx.x * blockDim.x + threadIdx.x; i < n4pairs;
         i += gridDim.x * blockDim.x) {
        float4 a = feat4[i * 2];
        float4 b = feat4[i * 2 + 1];
        half8 h;
        h[0] = (_Float16)a.x; h[1] = (_Float16)a.y;
        h[2] = (_Float16)a.z; h[3] = (_Float16)a.w;
        h[4] = (_Float16)b.x; h[5] = (_Float16)b.y;
        h[6] = (_Float16)b.z; h[7] = (_Float16)b.w;
        *reinterpret_cast<half8*>(&feat16[i]) = h;
    }
    __shared__ int h[NB];
    int c = blockIdx.x;
    if (c >= nchunk) return;
    for (int i = threadIdx.x; i < NB; i += blockDim.x) h[i] = 0;
    __syncthreads();
    int s = c * CHUNK, e = min(s + CHUNK, n_edges);
    for (int i = s + threadIdx.x; i < e; i += blockDim.x)
        atomicAdd(&h[dst[i] >> BSHIFT], 1);
    __syncthreads();
    for (int b = threadIdx.x; b < NB; b += blockDim.x)
        counts[(size_t)b * nchunk + c] = h[b];   // bucket-major
}

// ---------- K2: per-bucket exclusive scan over chunk counts ----------
__global__ void scanB(int* __restrict__ counts, int* __restrict__ totals, int nchunk) {
    __shared__ int s[256];
    int b = blockIdx.x;
    int tid = threadIdx.x;
    int carry = 0;
    int* row = counts + (size_t)b * nchunk;
    for (int t0 = 0; t0 < nchunk; t0 += 256) {
        int i = t0 + tid;
        int v = (i < nchunk) ? row[i] : 0;
        s[tid] = v;
        __syncthreads();
        for (int off = 1; off < 256; off <<= 1) {
            int t = (tid >= off) ? s[tid - off] : 0;
            __syncthreads();
            s[tid] += t;
            __syncthreads();
        }
        if (i < nchunk) row[i] = s[tid] - v + carry;
        carry += s[255];
        __syncthreads();
    }
    if (tid == 0) totals[b] = carry;
}

// ---------- K2b: exclusive scan of totals -> bucket base (one block, NB<=1024) ----------
__global__ void baseK(const int* __restrict__ totals, int* __restrict__ base,
                      int n_edges) {
    __shared__ int s[1024];
    int tid = threadIdx.x;
    int v = (tid < NB) ? totals[tid] : 0;
    s[tid] = v;
    __syncthreads();
    for (int off = 1; off < 1024; off <<= 1) {
        int t = (tid >= off) ? s[tid - off] : 0;
        __syncthreads();
        s[tid] += t;
        __syncthreads();
    }
    if (tid < NB) base[tid] = s[tid] - v;
    if (tid == 0) base[NB] = n_edges;
}

// ---------- K3: scatter to bucket order ----------
__global__ void scatter2(const int* __restrict__ src, const int* __restrict__ dst,
                         const int* __restrict__ counts, const int* __restrict__ base,
                         unsigned* __restrict__ sorted, int nchunk, int n_edges) {
    __shared__ int cur[NB];
    int tid = threadIdx.x;      // 1024
    int c = blockIdx.x;
    for (int b = tid; b < NB; b += blockDim.x)
        cur[b] = base[b] + counts[(size_t)b * nchunk + c];
    __syncthreads();
    int s = c * CHUNK, e = min(s + CHUNK, n_edges);
    for (int i = s + tid; i < e; i += blockDim.x) {
        int d = dst[i];
        int b = d >> BSHIFT;
        int r = atomicAdd(&cur[b], 1);
        sorted[r] = ((unsigned)(d & (BNODES - 1)) << 17) | (unsigned)src[i];
    }
}

// ---------- K4: per-bucket counting sort into LDS + fp16 gather ----------
// Gather: 128 groups of 8 lanes (16B half8/lane); each group interleaves its TWO
// nodes (g, g+128) with dual accumulators -> 8 independent loads in flight.
__global__ void sortGather(const _Float16* __restrict__ feat16,
                           const unsigned* __restrict__ sorted,
                           const int* __restrict__ base,
                           unsigned* __restrict__ sorted2,   // spill path only
                           float* __restrict__ out) {
    __shared__ int cnt[BNODES];
    __shared__ int scn[BNODES];
    __shared__ int noff[BNODES + 1];
    __shared__ int cur[BNODES];
    __shared__ unsigned lsrc[LDS_CAP];
    int tid = threadIdx.x;      // 1024
    int b = blockIdx.x;

    int start = base[b];
    int cntb = base[b + 1] - start;
    bool big = (cntb > LDS_CAP);

    // stage up to 4 edges/thread in registers (single global read of sorted)
    unsigned p0 = 0, p1 = 0, p2 = 0, p3 = 0;
    int i0 = tid, i1 = tid + 1024, i2 = tid + 2048, i3 = tid + 3072;
    if (!big) {
        if (i0 < cntb) p0 = sorted[start + i0];
        if (i1 < cntb) p1 = sorted[start + i1];
        if (i2 < cntb) p2 = sorted[start + i2];
        if (i3 < cntb) p3 = sorted[start + i3];
    }

    if (tid < BNODES) cnt[tid] = 0;
    __syncthreads();
    if (!big) {
        if (i0 < cntb) atomicAdd(&cnt[(p0 >> 17) & (BNODES - 1)], 1);
        if (i1 < cntb) atomicAdd(&cnt[(p1 >> 17) & (BNODES - 1)], 1);
        if (i2 < cntb) atomicAdd(&cnt[(p2 >> 17) & (BNODES - 1)], 1);
        if (i3 < cntb) atomicAdd(&cnt[(p3 >> 17) & (BNODES - 1)], 1);
    } else {
        for (int i = tid; i < cntb; i += 1024)
            atomicAdd(&cnt[(sorted[start + i] >> 17) & (BNODES - 1)], 1);
    }
    __syncthreads();

    // scan BNODES counts
    int v = (tid < BNODES) ? cnt[tid] : 0;
    if (tid < BNODES) scn[tid] = v;
    __syncthreads();
    for (int off = 1; off < BNODES; off <<= 1) {
        int t = 0;
        if (tid < BNODES && tid >= off) t = scn[tid - off];
        __syncthreads();
        if (tid < BNODES) scn[tid] += t;
        __syncthreads();
    }
    if (tid < BNODES) { noff[tid] = scn[tid] - v; cur[tid] = scn[tid] - v; }
    if (tid == 0) noff[BNODES] = cntb;
    __syncthreads();

    // place (src only; order within node irrelevant for a sum)
    if (!big) {
        if (i0 < cntb) { int q = atomicAdd(&cur[(p0 >> 17) & (BNODES - 1)], 1); lsrc[q] = p0 & 0x1FFFF; }
        if (i1 < cntb) { int q = atomicAdd(&cur[(p1 >> 17) & (BNODES - 1)], 1); lsrc[q] = p1 & 0x1FFFF; }
        if (i2 < cntb) { int q = atomicAdd(&cur[(p2 >> 17) & (BNODES - 1)], 1); lsrc[q] = p2 & 0x1FFFF; }
        if (i3 < cntb) { int q = atomicAdd(&cur[(p3 >> 17) & (BNODES - 1)], 1); lsrc[q] = p3 & 0x1FFFF; }
    } else {
        for (int i = tid; i < cntb; i += 1024) {
            unsigned p = sorted[start + i];
            int q = atomicAdd(&cur[(p >> 17) & (BNODES - 1)], 1);
            sorted2[start + q] = p & 0x1FFFF;
        }
    }
    __syncthreads();

    int g = tid >> 3, gl = tid & 7;     // 128 groups of 8 lanes
    int nA = g, nB = g + 128;
    int nodeA = (b << BSHIFT) + nA;
    int nodeB = (b << BSHIFT) + nB;

#define LOAD8(sidx) (*reinterpret_cast<const half8*>(&feat16[(size_t)(sidx) * D + gl * 8]))
#define ACC8(acLo, acHi, vv)                                                   \
    { acLo.x += (float)vv[0]; acLo.y += (float)vv[1];                          \
      acLo.z += (float)vv[2]; acLo.w += (float)vv[3];                          \
      acHi.x += (float)vv[4]; acHi.y += (float)vv[5];                          \
      acHi.z += (float)vv[6]; acHi.w += (float)vv[7]; }

    if (!big) {
        int offA = noff[nA], endA = noff[nA + 1];
        int offB = noff[nB], endB = noff[nB + 1];
        float4 aLo = make_float4(0.f, 0.f, 0.f, 0.f);
        float4 aHi = make_float4(0.f, 0.f, 0.f, 0.f);
        float4 bLo = make_float4(0.f, 0.f, 0.f, 0.f);
        float4 bHi = make_float4(0.f, 0.f, 0.f, 0.f);
        int eA = offA, eB = offB;

        // dual phase: 8 independent loads in flight
        while (eA + 4 <= endA && eB + 4 <= endB) {
            int sa0 = lsrc[eA], sa1 = lsrc[eA + 1], sa2 = lsrc[eA + 2], sa3 = lsrc[eA + 3];
            int sb0 = lsrc[eB], sb1 = lsrc[eB + 1], sb2 = lsrc[eB + 2], sb3 = lsrc[eB + 3];
            half8 va0 = LOAD8(sa0); half8 va1 = LOAD8(sa1);
            half8 va2 = LOAD8(sa2); half8 va3 = LOAD8(sa3);
            half8 vb0 = LOAD8(sb0); half8 vb1 = LOAD8(sb1);
            half8 vb2 = LOAD8(sb2); half8 vb3 = LOAD8(sb3);
            ACC8(aLo, aHi, va0) ACC8(aLo, aHi, va1) ACC8(aLo, aHi, va2) ACC8(aLo, aHi, va3)
            ACC8(bLo, bHi, vb0) ACC8(bLo, bHi, vb1) ACC8(bLo, bHi, vb2) ACC8(bLo, bHi, vb3)
            eA += 4; eB += 4;
        }
        // drain A
        for (; eA + 4 <= endA; eA += 4) {
            int s0 = lsrc[eA], s1 = lsrc[eA + 1], s2 = lsrc[eA + 2], s3 = lsrc[eA + 3];
            half8 v0 = LOAD8(s0); half8 v1 = LOAD8(s1);
            half8 v2 = LOAD8(s2); half8 v3 = LOAD8(s3);
            ACC8(aLo, aHi, v0) ACC8(aLo, aHi, v1) ACC8(aLo, aHi, v2) ACC8(aLo, aHi, v3)
        }
        for (; eA < endA; eA++) { half8 vv = LOAD8(lsrc[eA]); ACC8(aLo, aHi, vv) }
        // drain B
        for (; eB + 4 <= endB; eB += 4) {
            int s0 = lsrc[eB], s1 = lsrc[eB + 1], s2 = lsrc[eB + 2], s3 = lsrc[eB + 3];
            half8 v0 = LOAD8(s0); half8 v1 = LOAD8(s1);
            half8 v2 = LOAD8(s2); half8 v3 = LOAD8(s3);
            ACC8(bLo, bHi, v0) ACC8(bLo, bHi, v1) ACC8(bLo, bHi, v2) ACC8(bLo, bHi, v3)
        }
        for (; eB < endB; eB++) { half8 vv = LOAD8(lsrc[eB]); ACC8(bLo, bHi, vv) }

        if (nodeA < N_NODES) {
            int dg = endA - offA;
            float inv = (dg > 0) ? 1.0f / (float)dg : 0.0f;
            float* orow = &out[(size_t)nodeA * D + gl * 8];
            *reinterpret_cast<float4*>(orow) =
                make_float4(aLo.x * inv, aLo.y * inv, aLo.z * inv, aLo.w * inv);
            *reinterpret_cast<float4*>(orow + 4) =
                make_float4(aHi.x * inv, aHi.y * inv, aHi.z * inv, aHi.w * inv);
        }
        if (nodeB < N_NODES) {
            int dg = endB - offB;
            float inv = (dg > 0) ? 1.0f / (float)dg : 0.0f;
            float* orow = &out[(size_t)nodeB * D + gl * 8];
            *reinterpret_cast<float4*>(orow) =
                make_float4(bLo.x * inv, bLo.y * inv, bLo.z * inv, bLo.w * inv);
            *reinterpret_cast<float4*>(orow + 4) =
                make_float4(bHi.x * inv, bHi.y * inv, bHi.z * inv, bHi.w * inv);
        }
    } else {
        // rare spill path: per-node loop from global sorted2
        for (int n = g; n < BNODES; n += 128) {
            int node = (b << BSHIFT) + n;
            if (node >= N_NODES) break;
            int off = noff[n], endn = noff[n + 1];
            int deg = endn - off;
            float4 accA = make_float4(0.f, 0.f, 0.f, 0.f);
            float4 accB = make_float4(0.f, 0.f, 0.f, 0.f);
            for (int e = off; e < endn; e++) {
                int s = (int)sorted2[start + e];
                half8 vv = LOAD8(s);
                ACC8(accA, accB, vv)
            }
            float inv = (deg > 0) ? 1.0f / (float)deg : 0.0f;
            float* orow = &out[(size_t)node * D + gl * 8];
            *reinterpret_cast<float4*>(orow) =
                make_float4(accA.x * inv, accA.y * inv, accA.z * inv, accA.w * inv);
            *reinterpret_cast<float4*>(orow + 4) =
                make_float4(accB.x * inv, accB.y * inv, accB.z * inv, accB.w * inv);
        }
    }
#undef LOAD8
#undef ACC8
}

// ---------- fallback (atomic scatter) if ws too small ----------
__global__ void gcn_scatter(const float* __restrict__ feat, const int* __restrict__ src,
                            const int* __restrict__ dst, float* __restrict__ out,
                            float* __restrict__ deg, int n_edges) {
    long long gtid = (long long)blockIdx.x * blockDim.x + threadIdx.x;
    int edge = (int)(gtid >> 6);
    int lane = threadIdx.x & 63;
    if (edge >= n_edges) return;
    atomicAdd(&out[(long long)dst[edge] * D + lane],
              feat[(long long)src[edge] * D + lane]);
    if (lane == 0) atomicAdd(&deg[dst[edge]], 1.0f);
}
__global__ void gcn_finalize(float* __restrict__ out, const float* __restrict__ deg,
                             int total) {
    int i = blockIdx.x * blockDim.x + threadIdx.x;
    if (i >= total) return;
    float dg = deg[i >> 6];
    out[i] = (dg > 0.0f) ? out[i] / dg : 0.0f;
}

extern "C" void kernel_launch(void* const* d_in, const int* in_sizes, int n_in,
                              void* d_out, int out_size, void* d_ws, size_t ws_size,
                              hipStream_t stream) {
    const float* feat = (const float*)d_in[0];
    const int* src = (const int*)d_in[1];
    const int* dst = (const int*)d_in[2];
    float* out = (float*)d_out;
    int n_edges = in_sizes[1];

    int nchunk = (n_edges + CHUNK - 1) / CHUNK;
    size_t ncounts = (size_t)NB * nchunk;
    size_t f16_bytes = (size_t)N_NODES * D * sizeof(_Float16);   // 12.8 MB
    size_t need = f16_bytes + (ncounts + NB + NB + 1) * sizeof(int)
                + (size_t)n_edges * 2 * sizeof(unsigned);

    if (ws_size < need) {
        float* deg = (float*)d_ws;
        int total = N_NODES * D;
        hipMemsetAsync(out, 0, (size_t)total * sizeof(float), stream);
        hipMemsetAsync(deg, 0, (size_t)N_NODES * sizeof(float), stream);
        long long threads = (long long)n_edges * 64;
        int grid = (int)((threads + 255) / 256);
        gcn_scatter<<<grid, 256, 0, stream>>>(feat, src, dst, out, deg, n_edges);
        gcn_finalize<<<(total + 255) / 256, 256, 0, stream>>>(out, deg, total);
        return;
    }

    char* wp = (char*)d_ws;
    _Float16* feat16 = (_Float16*)wp;            wp += f16_bytes;
    int* counts = (int*)wp;                      wp += ncounts * sizeof(int);
    int* totals = (int*)wp;                      wp += (size_t)NB * sizeof(int);
    int* base = (int*)wp;                        wp += (size_t)(NB + 1) * sizeof(int);
    unsigned* sorted = (unsigned*)wp;            wp += (size_t)n_edges * sizeof(unsigned);
    unsigned* sorted2 = (unsigned*)wp;           // spill path only

    int n4pairs = N_NODES * D / 8;
    int chgrid = (nchunk > 256) ? nchunk : 256;
    convhist<<<chgrid, 1024, 0, stream>>>((const float4*)feat, (float4*)feat16,
                                          n4pairs, dst, counts, nchunk, n_edges);
    scanB<<<NB, 256, 0, stream>>>(counts, totals, nchunk);
    baseK<<<1, 1024, 0, stream>>>(totals, base, n_edges);
    scatter2<<<nchunk, 1024, 0, stream>>>(src, dst, counts, base, sorted,
                                          nchunk, n_edges);
    sortGather<<<NB, 1024, 0, stream>>>(feat16, sorted, base, sorted2, out);
}

// Round 15
// 56.436 us; speedup vs baseline: 1.5213x; 1.1566x over previous
//
#include <hip/hip_runtime.h>
#include <hip/hip_bf16.h>

#define N_NODES 100000
#define D 64
#define BSHIFT 8
#define BNODES 256        // nodes per bucket
#define NB 391            // ceil(100000/256)
#define CHUNK 8192
#define LDS_CAP 4096      // edges per bucket in LDS (mean 3200, sd ~56)

typedef __attribute__((ext_vector_type(8))) _Float16 half8;

// ---------- K1: role-split — hist blocks do hist only; extra blocks do conv only ----------
__global__ void convhist(const float4* __restrict__ feat4, float4* __restrict__ feat16,
                         int n4pairs, const int* __restrict__ dst, int* __restrict__ counts,
                         int nchunk, int n_edges) {
    int c = blockIdx.x;
    if (c >= nchunk) {
        // conv-only blocks
        int nb = gridDim.x - nchunk;
        int bi = c - nchunk;
        for (int i = bi * blockDim.x + threadIdx.x; i < n4pairs; i += nb * blockDim.x) {
            float4 a = feat4[i * 2];
            float4 b = feat4[i * 2 + 1];
            half8 h;
            h[0] = (_Float16)a.x; h[1] = (_Float16)a.y;
            h[2] = (_Float16)a.z; h[3] = (_Float16)a.w;
            h[4] = (_Float16)b.x; h[5] = (_Float16)b.y;
            h[6] = (_Float16)b.z; h[7] = (_Float16)b.w;
            *reinterpret_cast<half8*>(&feat16[i]) = h;
        }
        return;
    }
    // hist-only blocks
    __shared__ int h[NB];
    for (int i = threadIdx.x; i < NB; i += blockDim.x) h[i] = 0;
    __syncthreads();
    int s = c * CHUNK, e = min(s + CHUNK, n_edges);
    for (int i = s + threadIdx.x; i < e; i += blockDim.x)
        atomicAdd(&h[dst[i] >> BSHIFT], 1);
    __syncthreads();
    for (int b = threadIdx.x; b < NB; b += blockDim.x)
        counts[(size_t)b * nchunk + c] = h[b];   // bucket-major
}

// ---------- K2: per-bucket exclusive scan over chunk counts ----------
__global__ void scanB(int* __restrict__ counts, int* __restrict__ totals, int nchunk) {
    __shared__ int s[256];
    int b = blockIdx.x;
    int tid = threadIdx.x;
    int carry = 0;
    int* row = counts + (size_t)b * nchunk;
    for (int t0 = 0; t0 < nchunk; t0 += 256) {
        int i = t0 + tid;
        int v = (i < nchunk) ? row[i] : 0;
        s[tid] = v;
        __syncthreads();
        for (int off = 1; off < 256; off <<= 1) {
            int t = (tid >= off) ? s[tid - off] : 0;
            __syncthreads();
            s[tid] += t;
            __syncthreads();
        }
        if (i < nchunk) row[i] = s[tid] - v + carry;
        carry += s[255];
        __syncthreads();
    }
    if (tid == 0) totals[b] = carry;
}

// ---------- K2b: exclusive scan of totals -> bucket base (one block, NB<=1024) ----------
__global__ void baseK(const int* __restrict__ totals, int* __restrict__ base,
                      int n_edges) {
    __shared__ int s[1024];
    int tid = threadIdx.x;
    int v = (tid < NB) ? totals[tid] : 0;
    s[tid] = v;
    __syncthreads();
    for (int off = 1; off < 1024; off <<= 1) {
        int t = (tid >= off) ? s[tid - off] : 0;
        __syncthreads();
        s[tid] += t;
        __syncthreads();
    }
    if (tid < NB) base[tid] = s[tid] - v;
    if (tid == 0) base[NB] = n_edges;
}

// ---------- K3: scatter to bucket order, LDS-staged for coalesced writes ----------
__global__ void scatter2(const int* __restrict__ src, const int* __restrict__ dst,
                         const int* __restrict__ counts, const int* __restrict__ base,
                         unsigned* __restrict__ sorted, int nchunk, int n_edges) {
    __shared__ int lcnt[NB];
    __shared__ int lbase[NB];
    __shared__ int gb[NB];
    __shared__ int lcur[NB];
    __shared__ int scn[512];
    __shared__ unsigned sval[CHUNK];     // staged packed edges (32 KB)
    __shared__ unsigned sgad[CHUNK];     // staged global addresses (32 KB)
    int tid = threadIdx.x;               // 1024
    int c = blockIdx.x;
    int s = c * CHUNK, e = min(s + CHUNK, n_edges);

    for (int b = tid; b < NB; b += 1024) lcnt[b] = 0;
    __syncthreads();

    unsigned pv[8];
    short pb[8];
    #pragma unroll
    for (int k = 0; k < 8; k++) {
        int i = s + tid + k * 1024;
        if (i < e) {
            int d = dst[i];
            int b = d >> BSHIFT;
            pv[k] = ((unsigned)(d & (BNODES - 1)) << 17) | (unsigned)src[i];
            pb[k] = (short)b;
            atomicAdd(&lcnt[b], 1);
        } else pb[k] = -1;
    }
    __syncthreads();

    // exclusive scan of 391 local counts
    if (tid < 512) scn[tid] = (tid < NB) ? lcnt[tid] : 0;
    __syncthreads();
    for (int off = 1; off < 512; off <<= 1) {
        int t = 0;
        if (tid < 512 && tid >= off) t = scn[tid - off];
        __syncthreads();
        if (tid < 512) scn[tid] += t;
        __syncthreads();
    }
    if (tid < NB) {
        int excl = scn[tid] - lcnt[tid];
        lbase[tid] = excl;
        lcur[tid] = excl;
        // global addr = gb[b] + lds_slot
        gb[tid] = base[tid] + counts[(size_t)tid * nchunk + c] - excl;
    }
    __syncthreads();

    #pragma unroll
    for (int k = 0; k < 8; k++) {
        if (pb[k] >= 0) {
            int b = pb[k];
            int q = atomicAdd(&lcur[b], 1);
            sval[q] = pv[k];
            sgad[q] = (unsigned)(gb[b] + q);
        }
    }
    __syncthreads();

    int m = e - s;
    for (int i = tid; i < m; i += 1024)
        sorted[sgad[i]] = sval[i];
}

// ---------- K4: per-bucket counting sort into LDS + fp16 gather (R12, best) ----------
__global__ void sortGather(const _Float16* __restrict__ feat16,
                           const unsigned* __restrict__ sorted,
                           const int* __restrict__ base,
                           unsigned* __restrict__ sorted2,   // spill path only
                           float* __restrict__ out) {
    __shared__ int cnt[BNODES];
    __shared__ int scn[BNODES];
    __shared__ int noff[BNODES + 1];
    __shared__ int cur[BNODES];
    __shared__ unsigned lsrc[LDS_CAP];
    int tid = threadIdx.x;      // 1024
    int b = blockIdx.x;

    int start = base[b];
    int cntb = base[b + 1] - start;
    bool big = (cntb > LDS_CAP);

    unsigned p0 = 0, p1 = 0, p2 = 0, p3 = 0;
    int i0 = tid, i1 = tid + 1024, i2 = tid + 2048, i3 = tid + 3072;
    if (!big) {
        if (i0 < cntb) p0 = sorted[start + i0];
        if (i1 < cntb) p1 = sorted[start + i1];
        if (i2 < cntb) p2 = sorted[start + i2];
        if (i3 < cntb) p3 = sorted[start + i3];
    }

    if (tid < BNODES) cnt[tid] = 0;
    __syncthreads();
    if (!big) {
        if (i0 < cntb) atomicAdd(&cnt[(p0 >> 17) & (BNODES - 1)], 1);
        if (i1 < cntb) atomicAdd(&cnt[(p1 >> 17) & (BNODES - 1)], 1);
        if (i2 < cntb) atomicAdd(&cnt[(p2 >> 17) & (BNODES - 1)], 1);
        if (i3 < cntb) atomicAdd(&cnt[(p3 >> 17) & (BNODES - 1)], 1);
    } else {
        for (int i = tid; i < cntb; i += 1024)
            atomicAdd(&cnt[(sorted[start + i] >> 17) & (BNODES - 1)], 1);
    }
    __syncthreads();

    int v = (tid < BNODES) ? cnt[tid] : 0;
    if (tid < BNODES) scn[tid] = v;
    __syncthreads();
    for (int off = 1; off < BNODES; off <<= 1) {
        int t = 0;
        if (tid < BNODES && tid >= off) t = scn[tid - off];
        __syncthreads();
        if (tid < BNODES) scn[tid] += t;
        __syncthreads();
    }
    if (tid < BNODES) { noff[tid] = scn[tid] - v; cur[tid] = scn[tid] - v; }
    if (tid == 0) noff[BNODES] = cntb;
    __syncthreads();

    if (!big) {
        if (i0 < cntb) { int q = atomicAdd(&cur[(p0 >> 17) & (BNODES - 1)], 1); lsrc[q] = p0 & 0x1FFFF; }
        if (i1 < cntb) { int q = atomicAdd(&cur[(p1 >> 17) & (BNODES - 1)], 1); lsrc[q] = p1 & 0x1FFFF; }
        if (i2 < cntb) { int q = atomicAdd(&cur[(p2 >> 17) & (BNODES - 1)], 1); lsrc[q] = p2 & 0x1FFFF; }
        if (i3 < cntb) { int q = atomicAdd(&cur[(p3 >> 17) & (BNODES - 1)], 1); lsrc[q] = p3 & 0x1FFFF; }
    } else {
        for (int i = tid; i < cntb; i += 1024) {
            unsigned p = sorted[start + i];
            int q = atomicAdd(&cur[(p >> 17) & (BNODES - 1)], 1);
            sorted2[start + q] = p & 0x1FFFF;
        }
    }
    __syncthreads();

    // gather: 128 groups of 8 lanes; lane covers 8 fp16 (16B load); 2 nodes per group
    int g = tid >> 3, gl = tid & 7;
    for (int n = g; n < BNODES; n += 128) {
        int node = (b << BSHIFT) + n;
        if (node >= N_NODES) break;
        int off = noff[n], endn = noff[n + 1];
        int deg = endn - off;
        float4 accA = make_float4(0.f, 0.f, 0.f, 0.f);
        float4 accB = make_float4(0.f, 0.f, 0.f, 0.f);
        int e = off;
        if (!big) {
            for (; e + 4 <= endn; e += 4) {
                int s0 = lsrc[e], s1 = lsrc[e + 1], s2 = lsrc[e + 2], s3 = lsrc[e + 3];
                half8 v0 = *reinterpret_cast<const half8*>(&feat16[(size_t)s0 * D + gl * 8]);
                half8 v1 = *reinterpret_cast<const half8*>(&feat16[(size_t)s1 * D + gl * 8]);
                half8 v2 = *reinterpret_cast<const half8*>(&feat16[(size_t)s2 * D + gl * 8]);
                half8 v3 = *reinterpret_cast<const half8*>(&feat16[(size_t)s3 * D + gl * 8]);
                accA.x += (float)v0[0] + (float)v1[0] + (float)v2[0] + (float)v3[0];
                accA.y += (float)v0[1] + (float)v1[1] + (float)v2[1] + (float)v3[1];
                accA.z += (float)v0[2] + (float)v1[2] + (float)v2[2] + (float)v3[2];
                accA.w += (float)v0[3] + (float)v1[3] + (float)v2[3] + (float)v3[3];
                accB.x += (float)v0[4] + (float)v1[4] + (float)v2[4] + (float)v3[4];
                accB.y += (float)v0[5] + (float)v1[5] + (float)v2[5] + (float)v3[5];
                accB.z += (float)v0[6] + (float)v1[6] + (float)v2[6] + (float)v3[6];
                accB.w += (float)v0[7] + (float)v1[7] + (float)v2[7] + (float)v3[7];
            }
            for (; e < endn; e++) {
                int s = lsrc[e];
                half8 vv = *reinterpret_cast<const half8*>(&feat16[(size_t)s * D + gl * 8]);
                accA.x += (float)vv[0]; accA.y += (float)vv[1];
                accA.z += (float)vv[2]; accA.w += (float)vv[3];
                accB.x += (float)vv[4]; accB.y += (float)vv[5];
                accB.z += (float)vv[6]; accB.w += (float)vv[7];
            }
        } else {
            for (; e < endn; e++) {
                int s = (int)sorted2[start + e];
                half8 vv = *reinterpret_cast<const half8*>(&feat16[(size_t)s * D + gl * 8]);
                accA.x += (float)vv[0]; accA.y += (float)vv[1];
                accA.z += (float)vv[2]; accA.w += (float)vv[3];
                accB.x += (float)vv[4]; accB.y += (float)vv[5];
                accB.z += (float)vv[6]; accB.w += (float)vv[7];
            }
        }
        float inv = (deg > 0) ? 1.0f / (float)deg : 0.0f;
        float4 oA = make_float4(accA.x * inv, accA.y * inv, accA.z * inv, accA.w * inv);
        float4 oB = make_float4(accB.x * inv, accB.y * inv, accB.z * inv, accB.w * inv);
        float* orow = &out[(size_t)node * D + gl * 8];
        *reinterpret_cast<float4*>(orow) = oA;
        *reinterpret_cast<float4*>(orow + 4) = oB;
    }
}

// ---------- fallback (atomic scatter) if ws too small ----------
__global__ void gcn_scatter(const float* __restrict__ feat, const int* __restrict__ src,
                            const int* __restrict__ dst, float* __restrict__ out,
                            float* __restrict__ deg, int n_edges) {
    long long gtid = (long long)blockIdx.x * blockDim.x + threadIdx.x;
    int edge = (int)(gtid >> 6);
    int lane = threadIdx.x & 63;
    if (edge >= n_edges) return;
    atomicAdd(&out[(long long)dst[edge] * D + lane],
              feat[(long long)src[edge] * D + lane]);
    if (lane == 0) atomicAdd(&deg[dst[edge]], 1.0f);
}
__global__ void gcn_finalize(float* __restrict__ out, const float* __restrict__ deg,
                             int total) {
    int i = blockIdx.x * blockDim.x + threadIdx.x;
    if (i >= total) return;
    float dg = deg[i >> 6];
    out[i] = (dg > 0.0f) ? out[i] / dg : 0.0f;
}

extern "C" void kernel_launch(void* const* d_in, const int* in_sizes, int n_in,
                              void* d_out, int out_size, void* d_ws, size_t ws_size,
                              hipStream_t stream) {
    const float* feat = (const float*)d_in[0];
    const int* src = (const int*)d_in[1];
    const int* dst = (const int*)d_in[2];
    float* out = (float*)d_out;
    int n_edges = in_sizes[1];

    int nchunk = (n_edges + CHUNK - 1) / CHUNK;
    size_t ncounts = (size_t)NB * nchunk;
    size_t f16_bytes = (size_t)N_NODES * D * sizeof(_Float16);   // 12.8 MB
    size_t need = f16_bytes + (ncounts + NB + NB + 1) * sizeof(int)
                + (size_t)n_edges * 2 * sizeof(unsigned);

    if (ws_size < need) {
        float* deg = (float*)d_ws;
        int total = N_NODES * D;
        hipMemsetAsync(out, 0, (size_t)total * sizeof(float), stream);
        hipMemsetAsync(deg, 0, (size_t)N_NODES * sizeof(float), stream);
        long long threads = (long long)n_edges * 64;
        int grid = (int)((threads + 255) / 256);
        gcn_scatter<<<grid, 256, 0, stream>>>(feat, src, dst, out, deg, n_edges);
        gcn_finalize<<<(total + 255) / 256, 256, 0, stream>>>(out, deg, total);
        return;
    }

    char* wp = (char*)d_ws;
    _Float16* feat16 = (_Float16*)wp;            wp += f16_bytes;
    int* counts = (int*)wp;                      wp += ncounts * sizeof(int);
    int* totals = (int*)wp;                      wp += (size_t)NB * sizeof(int);
    int* base = (int*)wp;                        wp += (size_t)(NB + 1) * sizeof(int);
    unsigned* sorted = (unsigned*)wp;            wp += (size_t)n_edges * sizeof(unsigned);
    unsigned* sorted2 = (unsigned*)wp;           // spill path only

    int n4pairs = N_NODES * D / 8;
    int chgrid = nchunk + 128;                   // hist blocks + dedicated conv blocks
    convhist<<<chgrid, 1024, 0, stream>>>((const float4*)feat, (float4*)feat16,
                                          n4pairs, dst, counts, nchunk, n_edges);
    scanB<<<NB, 256, 0, stream>>>(counts, totals, nchunk);
    baseK<<<1, 1024, 0, stream>>>(totals, base, n_edges);
    scatter2<<<nchunk, 1024, 0, stream>>>(src, dst, counts, base, sorted,
                                          nchunk, n_edges);
    sortGather<<<NB, 1024, 0, stream>>>(feat16, sorted, base, sorted2, out);
}

// Round 16
// 54.756 us; speedup vs baseline: 1.5680x; 1.0307x over previous
//
#include <hip/hip_runtime.h>
#include <hip/hip_bf16.h>

#define N_NODES 100000
#define D 64
#define BSHIFT 8
#define BNODES 256        // nodes per bucket
#define NB 391            // ceil(100000/256)
#define CHUNK 8192
#define LDS_CAP 4096      // edges per bucket in LDS (mean 3200, sd ~56)

typedef __attribute__((ext_vector_type(8))) _Float16 half8;

// ---------- K1: role-split — hist blocks (int4 reads) / conv-only blocks ----------
__global__ void convhist(const float4* __restrict__ feat4, float4* __restrict__ feat16,
                         int n4pairs, const int* __restrict__ dst, int* __restrict__ counts,
                         int nchunk, int n_edges) {
    int c = blockIdx.x;
    if (c >= nchunk) {
        int nb = gridDim.x - nchunk;
        int bi = c - nchunk;
        for (int i = bi * blockDim.x + threadIdx.x; i < n4pairs; i += nb * blockDim.x) {
            float4 a = feat4[i * 2];
            float4 b = feat4[i * 2 + 1];
            half8 h;
            h[0] = (_Float16)a.x; h[1] = (_Float16)a.y;
            h[2] = (_Float16)a.z; h[3] = (_Float16)a.w;
            h[4] = (_Float16)b.x; h[5] = (_Float16)b.y;
            h[6] = (_Float16)b.z; h[7] = (_Float16)b.w;
            *reinterpret_cast<half8*>(&feat16[i]) = h;
        }
        return;
    }
    __shared__ int h[NB];
    int tid = threadIdx.x;
    for (int i = tid; i < NB; i += blockDim.x) h[i] = 0;
    __syncthreads();
    int s = c * CHUNK, e = min(s + CHUNK, n_edges);
    int m = e - s;
    const int4* d4 = reinterpret_cast<const int4*>(dst + s);   // s is 8192-aligned
    int nv = m >> 2;
    for (int k = tid; k < nv; k += blockDim.x) {
        int4 dv = d4[k];
        atomicAdd(&h[dv.x >> BSHIFT], 1);
        atomicAdd(&h[dv.y >> BSHIFT], 1);
        atomicAdd(&h[dv.z >> BSHIFT], 1);
        atomicAdd(&h[dv.w >> BSHIFT], 1);
    }
    for (int i = s + (nv << 2) + tid; i < e; i += blockDim.x)
        atomicAdd(&h[dst[i] >> BSHIFT], 1);
    __syncthreads();
    for (int b = tid; b < NB; b += blockDim.x)
        counts[(size_t)b * nchunk + c] = h[b];   // bucket-major
}

// ---------- K2: per-bucket exclusive scan over chunk counts ----------
__global__ void scanB(int* __restrict__ counts, int* __restrict__ totals, int nchunk) {
    __shared__ int s[256];
    int b = blockIdx.x;
    int tid = threadIdx.x;
    int carry = 0;
    int* row = counts + (size_t)b * nchunk;
    for (int t0 = 0; t0 < nchunk; t0 += 256) {
        int i = t0 + tid;
        int v = (i < nchunk) ? row[i] : 0;
        s[tid] = v;
        __syncthreads();
        for (int off = 1; off < 256; off <<= 1) {
            int t = (tid >= off) ? s[tid - off] : 0;
            __syncthreads();
            s[tid] += t;
            __syncthreads();
        }
        if (i < nchunk) row[i] = s[tid] - v + carry;
        carry += s[255];
        __syncthreads();
    }
    if (tid == 0) totals[b] = carry;
}

// ---------- K2b: exclusive scan of totals -> bucket base (one block, NB<=1024) ----------
__global__ void baseK(const int* __restrict__ totals, int* __restrict__ base,
                      int n_edges) {
    __shared__ int s[1024];
    int tid = threadIdx.x;
    int v = (tid < NB) ? totals[tid] : 0;
    s[tid] = v;
    __syncthreads();
    for (int off = 1; off < 1024; off <<= 1) {
        int t = (tid >= off) ? s[tid - off] : 0;
        __syncthreads();
        s[tid] += t;
        __syncthreads();
    }
    if (tid < NB) base[tid] = s[tid] - v;
    if (tid == 0) base[NB] = n_edges;
}

// ---------- K3: scatter to bucket order, int4 reads + LDS-staged coalesced writes ----------
__global__ void scatter2(const int* __restrict__ src, const int* __restrict__ dst,
                         const int* __restrict__ counts, const int* __restrict__ base,
                         unsigned* __restrict__ sorted, int nchunk, int n_edges) {
    __shared__ int lcnt[NB];
    __shared__ int gb[NB];
    __shared__ int lcur[NB];
    __shared__ int scn[512];
    __shared__ unsigned sval[CHUNK];     // staged packed edges (32 KB)
    __shared__ unsigned sgad[CHUNK];     // staged global addresses (32 KB)
    int tid = threadIdx.x;               // 1024
    int c = blockIdx.x;
    int s = c * CHUNK, e = min(s + CHUNK, n_edges);

    for (int b = tid; b < NB; b += 1024) lcnt[b] = 0;
    __syncthreads();

    unsigned pv[8];
    short pb[8];
    #pragma unroll
    for (int p = 0; p < 2; p++) {
        int i0 = s + p * 4096 + tid * 4;
        if (i0 + 3 < e) {
            int4 dv = *reinterpret_cast<const int4*>(dst + i0);
            int4 sv = *reinterpret_cast<const int4*>(src + i0);
            int b0 = dv.x >> BSHIFT, b1 = dv.y >> BSHIFT,
                b2 = dv.z >> BSHIFT, b3 = dv.w >> BSHIFT;
            pv[p * 4 + 0] = ((unsigned)(dv.x & (BNODES - 1)) << 17) | (unsigned)sv.x;
            pv[p * 4 + 1] = ((unsigned)(dv.y & (BNODES - 1)) << 17) | (unsigned)sv.y;
            pv[p * 4 + 2] = ((unsigned)(dv.z & (BNODES - 1)) << 17) | (unsigned)sv.z;
            pv[p * 4 + 3] = ((unsigned)(dv.w & (BNODES - 1)) << 17) | (unsigned)sv.w;
            pb[p * 4 + 0] = (short)b0; pb[p * 4 + 1] = (short)b1;
            pb[p * 4 + 2] = (short)b2; pb[p * 4 + 3] = (short)b3;
            atomicAdd(&lcnt[b0], 1); atomicAdd(&lcnt[b1], 1);
            atomicAdd(&lcnt[b2], 1); atomicAdd(&lcnt[b3], 1);
        } else {
            #pragma unroll
            for (int j = 0; j < 4; j++) {
                int i = i0 + j;
                if (i < e) {
                    int d = dst[i];
                    int b = d >> BSHIFT;
                    pv[p * 4 + j] = ((unsigned)(d & (BNODES - 1)) << 17) | (unsigned)src[i];
                    pb[p * 4 + j] = (short)b;
                    atomicAdd(&lcnt[b], 1);
                } else pb[p * 4 + j] = -1;
            }
        }
    }
    __syncthreads();

    // exclusive scan of 391 local counts
    if (tid < 512) scn[tid] = (tid < NB) ? lcnt[tid] : 0;
    __syncthreads();
    for (int off = 1; off < 512; off <<= 1) {
        int t = 0;
        if (tid < 512 && tid >= off) t = scn[tid - off];
        __syncthreads();
        if (tid < 512) scn[tid] += t;
        __syncthreads();
    }
    if (tid < NB) {
        int excl = scn[tid] - lcnt[tid];
        lcur[tid] = excl;
        gb[tid] = base[tid] + counts[(size_t)tid * nchunk + c] - excl;
    }
    __syncthreads();

    #pragma unroll
    for (int k = 0; k < 8; k++) {
        if (pb[k] >= 0) {
            int b = pb[k];
            int q = atomicAdd(&lcur[b], 1);
            sval[q] = pv[k];
            sgad[q] = (unsigned)(gb[b] + q);
        }
    }
    __syncthreads();

    int m = e - s;
    for (int i = tid; i < m; i += 1024)
        sorted[sgad[i]] = sval[i];
}

// ---------- K4: per-bucket counting sort into LDS + fp16 gather (R12 form, best) ----------
__global__ void sortGather(const _Float16* __restrict__ feat16,
                           const unsigned* __restrict__ sorted,
                           const int* __restrict__ base,
                           unsigned* __restrict__ sorted2,   // spill path only
                           float* __restrict__ out) {
    __shared__ int cnt[BNODES];
    __shared__ int scn[BNODES];
    __shared__ int noff[BNODES + 1];
    __shared__ int cur[BNODES];
    __shared__ unsigned lsrc[LDS_CAP];
    int tid = threadIdx.x;      // 1024
    int b = blockIdx.x;

    int start = base[b];
    int cntb = base[b + 1] - start;
    bool big = (cntb > LDS_CAP);

    unsigned p0 = 0, p1 = 0, p2 = 0, p3 = 0;
    int i0 = tid, i1 = tid + 1024, i2 = tid + 2048, i3 = tid + 3072;
    if (!big) {
        if (i0 < cntb) p0 = sorted[start + i0];
        if (i1 < cntb) p1 = sorted[start + i1];
        if (i2 < cntb) p2 = sorted[start + i2];
        if (i3 < cntb) p3 = sorted[start + i3];
    }

    if (tid < BNODES) cnt[tid] = 0;
    __syncthreads();
    if (!big) {
        if (i0 < cntb) atomicAdd(&cnt[(p0 >> 17) & (BNODES - 1)], 1);
        if (i1 < cntb) atomicAdd(&cnt[(p1 >> 17) & (BNODES - 1)], 1);
        if (i2 < cntb) atomicAdd(&cnt[(p2 >> 17) & (BNODES - 1)], 1);
        if (i3 < cntb) atomicAdd(&cnt[(p3 >> 17) & (BNODES - 1)], 1);
    } else {
        for (int i = tid; i < cntb; i += 1024)
            atomicAdd(&cnt[(sorted[start + i] >> 17) & (BNODES - 1)], 1);
    }
    __syncthreads();

    int v = (tid < BNODES) ? cnt[tid] : 0;
    if (tid < BNODES) scn[tid] = v;
    __syncthreads();
    for (int off = 1; off < BNODES; off <<= 1) {
        int t = 0;
        if (tid < BNODES && tid >= off) t = scn[tid - off];
        __syncthreads();
        if (tid < BNODES) scn[tid] += t;
        __syncthreads();
    }
    if (tid < BNODES) { noff[tid] = scn[tid] - v; cur[tid] = scn[tid] - v; }
    if (tid == 0) noff[BNODES] = cntb;
    __syncthreads();

    if (!big) {
        if (i0 < cntb) { int q = atomicAdd(&cur[(p0 >> 17) & (BNODES - 1)], 1); lsrc[q] = p0 & 0x1FFFF; }
        if (i1 < cntb) { int q = atomicAdd(&cur[(p1 >> 17) & (BNODES - 1)], 1); lsrc[q] = p1 & 0x1FFFF; }
        if (i2 < cntb) { int q = atomicAdd(&cur[(p2 >> 17) & (BNODES - 1)], 1); lsrc[q] = p2 & 0x1FFFF; }
        if (i3 < cntb) { int q = atomicAdd(&cur[(p3 >> 17) & (BNODES - 1)], 1); lsrc[q] = p3 & 0x1FFFF; }
    } else {
        for (int i = tid; i < cntb; i += 1024) {
            unsigned p = sorted[start + i];
            int q = atomicAdd(&cur[(p >> 17) & (BNODES - 1)], 1);
            sorted2[start + q] = p & 0x1FFFF;
        }
    }
    __syncthreads();

    // gather: 128 groups of 8 lanes; lane covers 8 fp16 (16B load); 2 nodes per group
    int g = tid >> 3, gl = tid & 7;
    for (int n = g; n < BNODES; n += 128) {
        int node = (b << BSHIFT) + n;
        if (node >= N_NODES) break;
        int off = noff[n], endn = noff[n + 1];
        int deg = endn - off;
        float4 accA = make_float4(0.f, 0.f, 0.f, 0.f);
        float4 accB = make_float4(0.f, 0.f, 0.f, 0.f);
        int e = off;
        if (!big) {
            for (; e + 4 <= endn; e += 4) {
                int s0 = lsrc[e], s1 = lsrc[e + 1], s2 = lsrc[e + 2], s3 = lsrc[e + 3];
                half8 v0 = *reinterpret_cast<const half8*>(&feat16[(size_t)s0 * D + gl * 8]);
                half8 v1 = *reinterpret_cast<const half8*>(&feat16[(size_t)s1 * D + gl * 8]);
                half8 v2 = *reinterpret_cast<const half8*>(&feat16[(size_t)s2 * D + gl * 8]);
                half8 v3 = *reinterpret_cast<const half8*>(&feat16[(size_t)s3 * D + gl * 8]);
                accA.x += (float)v0[0] + (float)v1[0] + (float)v2[0] + (float)v3[0];
                accA.y += (float)v0[1] + (float)v1[1] + (float)v2[1] + (float)v3[1];
                accA.z += (float)v0[2] + (float)v1[2] + (float)v2[2] + (float)v3[2];
                accA.w += (float)v0[3] + (float)v1[3] + (float)v2[3] + (float)v3[3];
                accB.x += (float)v0[4] + (float)v1[4] + (float)v2[4] + (float)v3[4];
                accB.y += (float)v0[5] + (float)v1[5] + (float)v2[5] + (float)v3[5];
                accB.z += (float)v0[6] + (float)v1[6] + (float)v2[6] + (float)v3[6];
                accB.w += (float)v0[7] + (float)v1[7] + (float)v2[7] + (float)v3[7];
            }
            for (; e < endn; e++) {
                int s = lsrc[e];
                half8 vv = *reinterpret_cast<const half8*>(&feat16[(size_t)s * D + gl * 8]);
                accA.x += (float)vv[0]; accA.y += (float)vv[1];
                accA.z += (float)vv[2]; accA.w += (float)vv[3];
                accB.x += (float)vv[4]; accB.y += (float)vv[5];
                accB.z += (float)vv[6]; accB.w += (float)vv[7];
            }
        } else {
            for (; e < endn; e++) {
                int s = (int)sorted2[start + e];
                half8 vv = *reinterpret_cast<const half8*>(&feat16[(size_t)s * D + gl * 8]);
                accA.x += (float)vv[0]; accA.y += (float)vv[1];
                accA.z += (float)vv[2]; accA.w += (float)vv[3];
                accB.x += (float)vv[4]; accB.y += (float)vv[5];
                accB.z += (float)vv[6]; accB.w += (float)vv[7];
            }
        }
        float inv = (deg > 0) ? 1.0f / (float)deg : 0.0f;
        float4 oA = make_float4(accA.x * inv, accA.y * inv, accA.z * inv, accA.w * inv);
        float4 oB = make_float4(accB.x * inv, accB.y * inv, accB.z * inv, accB.w * inv);
        float* orow = &out[(size_t)node * D + gl * 8];
        *reinterpret_cast<float4*>(orow) = oA;
        *reinterpret_cast<float4*>(orow + 4) = oB;
    }
}

// ---------- fallback (atomic scatter) if ws too small ----------
__global__ void gcn_scatter(const float* __restrict__ feat, const int* __restrict__ src,
                            const int* __restrict__ dst, float* __restrict__ out,
                            float* __restrict__ deg, int n_edges) {
    long long gtid = (long long)blockIdx.x * blockDim.x + threadIdx.x;
    int edge = (int)(gtid >> 6);
    int lane = threadIdx.x & 63;
    if (edge >= n_edges) return;
    atomicAdd(&out[(long long)dst[edge] * D + lane],
              feat[(long long)src[edge] * D + lane]);
    if (lane == 0) atomicAdd(&deg[dst[edge]], 1.0f);
}
__global__ void gcn_finalize(float* __restrict__ out, const float* __restrict__ deg,
                             int total) {
    int i = blockIdx.x * blockDim.x + threadIdx.x;
    if (i >= total) return;
    float dg = deg[i >> 6];
    out[i] = (dg > 0.0f) ? out[i] / dg : 0.0f;
}

extern "C" void kernel_launch(void* const* d_in, const int* in_sizes, int n_in,
                              void* d_out, int out_size, void* d_ws, size_t ws_size,
                              hipStream_t stream) {
    const float* feat = (const float*)d_in[0];
    const int* src = (const int*)d_in[1];
    const int* dst = (const int*)d_in[2];
    float* out = (float*)d_out;
    int n_edges = in_sizes[1];

    int nchunk = (n_edges + CHUNK - 1) / CHUNK;
    size_t ncounts = (size_t)NB * nchunk;
    size_t f16_bytes = (size_t)N_NODES * D * sizeof(_Float16);   // 12.8 MB
    size_t need = f16_bytes + (ncounts + NB + NB + 1) * sizeof(int)
                + (size_t)n_edges * 2 * sizeof(unsigned);

    if (ws_size < need) {
        float* deg = (float*)d_ws;
        int total = N_NODES * D;
        hipMemsetAsync(out, 0, (size_t)total * sizeof(float), stream);
        hipMemsetAsync(deg, 0, (size_t)N_NODES * sizeof(float), stream);
        long long threads = (long long)n_edges * 64;
        int grid = (int)((threads + 255) / 256);
        gcn_scatter<<<grid, 256, 0, stream>>>(feat, src, dst, out, deg, n_edges);
        gcn_finalize<<<(total + 255) / 256, 256, 0, stream>>>(out, deg, total);
        return;
    }

    char* wp = (char*)d_ws;
    _Float16* feat16 = (_Float16*)wp;            wp += f16_bytes;
    int* counts = (int*)wp;                      wp += ncounts * sizeof(int);
    int* totals = (int*)wp;                      wp += (size_t)NB * sizeof(int);
    int* base = (int*)wp;                        wp += (size_t)(NB + 1) * sizeof(int);
    unsigned* sorted = (unsigned*)wp;            wp += (size_t)n_edges * sizeof(unsigned);
    unsigned* sorted2 = (unsigned*)wp;           // spill path only

    int n4pairs = N_NODES * D / 8;
    int chgrid = nchunk + 256;                   // hist blocks + 256 dedicated conv blocks
    convhist<<<chgrid, 1024, 0, stream>>>((const float4*)feat, (float4*)feat16,
                                          n4pairs, dst, counts, nchunk, n_edges);
    scanB<<<NB, 256, 0, stream>>>(counts, totals, nchunk);
    baseK<<<1, 1024, 0, stream>>>(totals, base, n_edges);
    scatter2<<<nchunk, 1024, 0, stream>>>(src, dst, counts, base, sorted,
                                          nchunk, n_edges);
    sortGather<<<NB, 1024, 0, stream>>>(feat16, sorted, base, sorted2, out);
}